// Round 4
// baseline (217.449 us; speedup 1.0000x reference)
//
#include <hip/hip_runtime.h>
#include <math.h>

// ---------------- workspace layout (bytes) ----------------
#define O_CNT    (0)                  // N ints (200KB)
#define O_ROWPTR (256*1024)           // N+1 ints
#define O_DINV   (512*1024)           // N floats
#define O_SMALL  (768*1024)           // few KB
#define O_GHIST  (1024*1024)          // 256*NB ints (~200KB)
#define O_GOFF   (1280*1024)          // 256*NB ints (~200KB)
#define O_SORT   (1536*1024)          // E uints = 3.2MB (aliased: PART after fill2)
#define O_PART   (1536*1024)          // 2048*132*4 = 1.08MB (alias of SORT)
#define O_XS     (4800*1024)          // N float4 = 800KB
#define O_COL    (5760*1024)          // E ints = 3.2MB
#define O_H1     (9216*1024)          // (N+1)*64 uints = 12.8MB + zero row
// small[] float indices:
//   [0..127] w2qk  [128] bias  [132..259] S  [260] R  [264..391] new_trainOT

#define LAYER2_BLOCKS 2048
#define NCHUNK 256

static __device__ __forceinline__ unsigned int f2bf(float f) {
    unsigned int u = __float_as_uint(f);
    return (u + 0x7fffu + ((u >> 16) & 1u)) >> 16;            // RNE
}
static __device__ __forceinline__ float bf_lo(unsigned int w) { return __uint_as_float(w << 16); }
static __device__ __forceinline__ float bf_hi(unsigned int w) { return __uint_as_float(w & 0xffff0000u); }

// ---------------- CSR build: phase A1 — per-chunk bucket histogram + global degree count ----------------
__global__ void k_hist(const int* __restrict__ dst, int* __restrict__ cnt,
                       int* __restrict__ ghist, int E, int CS, int NB) {
    __shared__ int lh[256];
    int b = blockIdx.x, t = threadIdx.x;
    lh[t] = 0; __syncthreads();
    int s = b * CS, e = min(E, s + CS);
    for (int i = s + t; i < e; i += 256) {
        int d = dst[i];
        atomicAdd(&cnt[d], 1);          // in-degree (merged old k_count)
        atomicAdd(&lh[d >> 8], 1);      // bucket histogram (LDS)
    }
    __syncthreads();
    if (t < NB) ghist[b * NB + t] = lh[t];
}

// ---------------- phase A2 — exclusive scan of hist in (bucket, chunk) order ----------------
__global__ void k_hscan(const int* __restrict__ ghist, int* __restrict__ goff, int NB) {
    __shared__ int wsum[16];
    __shared__ int carry_s;
    __shared__ int tot_s;
    int t = threadIdx.x, lane = t & 63, wid = t >> 6;
    int TOT = NB * 256;
    if (t == 0) carry_s = 0;
    __syncthreads();
    const int PER = 16, CHUNK = 1024 * PER;
    for (int base = 0; base < TOT; base += CHUNK) {
        int i0 = base + t * PER;
        int v[PER]; int s8 = 0;
#pragma unroll
        for (int k = 0; k < PER; ++k) {
            int idx = i0 + k;
            v[k] = (idx < TOT) ? ghist[(idx & 255) * NB + (idx >> 8)] : 0;
            s8 += v[k];
        }
        int incl = s8;
#pragma unroll
        for (int off = 1; off < 64; off <<= 1) {
            int n2 = __shfl_up(incl, off);
            if (lane >= off) incl += n2;
        }
        if (lane == 63) wsum[wid] = incl;
        __syncthreads();
        if (wid == 0) {
            int wv = (lane < 16) ? wsum[lane] : 0;
            int wincl = wv;
#pragma unroll
            for (int off = 1; off < 16; off <<= 1) {
                int n2 = __shfl_up(wincl, off);
                if (lane >= off) wincl += n2;
            }
            if (lane < 16) wsum[lane] = wincl - wv;   // exclusive
            if (lane == 15) tot_s = wincl;
        }
        __syncthreads();
        int run = carry_s + wsum[wid] + (incl - s8);  // exclusive prefix at thread start
#pragma unroll
        for (int k = 0; k < PER; ++k) {
            int idx = i0 + k;
            if (idx < TOT) goff[(idx & 255) * NB + (idx >> 8)] = run;
            run += v[k];
        }
        __syncthreads();
        if (t == 0) carry_s += tot_s;
        __syncthreads();
    }
}

// ---------------- phase A3 — scatter edges into bucket-sorted runs ----------------
__global__ void k_scatter(const int* __restrict__ src, const int* __restrict__ dst,
                          const int* __restrict__ goff, unsigned int* __restrict__ sorted,
                          int E, int CS, int NB) {
    __shared__ int lcur[256];
    int b = blockIdx.x, t = threadIdx.x;
    if (t < NB) lcur[t] = goff[b * NB + t];
    __syncthreads();
    int s = b * CS, e = min(E, s + CS);
    for (int i = s + t; i < e; i += 256) {
        int d = dst[i];
        int pos = atomicAdd(&lcur[d >> 8], 1);
        sorted[pos] = ((unsigned int)(d & 255) << 16) | (unsigned int)src[i];   // N <= 65536
    }
}

// ---------------- phase B — per-bucket regroup into final CSR (localized writes) ----------------
__global__ void k_fill2(const unsigned int* __restrict__ sorted, const int* __restrict__ goff,
                        const int* __restrict__ row_ptr, int* __restrict__ col, int E, int NB) {
    __shared__ int lcnt[256];
    int nb = blockIdx.x, t = threadIdx.x;
    lcnt[t] = 0; __syncthreads();
    int s = goff[nb];                               // bucket start (chunk 0)
    int e = (nb + 1 < NB) ? goff[nb + 1] : E;
    int dbase = nb << 8;
    for (int i = s + t; i < e; i += 256) {
        unsigned int v = sorted[i];
        int dl = v >> 16;
        int p = row_ptr[dbase + dl] + atomicAdd(&lcnt[dl], 1);
        col[p] = (int)(v & 0xffffu);
    }
}

// dinv + pre-scaled packed features + zero h1 row + out = bs init
__global__ void k_prep(const int* __restrict__ cnt, const float* __restrict__ x,
                       const float* __restrict__ bs, float* __restrict__ out,
                       float* __restrict__ dinv, float4* __restrict__ xs4,
                       unsigned int* __restrict__ h1s, int N) {
    int i = blockIdx.x * blockDim.x + threadIdx.x;
    if (i < N) {
        float d = rsqrtf((float)(cnt[i] + 1));   // +1 self-loop
        dinv[i] = d;
        float4 v;
        v.x = x[i * 3] * d; v.y = x[i * 3 + 1] * d; v.z = x[i * 3 + 2] * d; v.w = 0.f;
        xs4[i] = v;
        reinterpret_cast<float2*>(out)[i] = reinterpret_cast<const float2*>(bs)[i];  // out_n == 2N
    }
    if (i < 64) h1s[(size_t)N * 64 + i] = 0u;    // zero row for ragged-tail gathers
}

static __device__ __forceinline__ int4 ld_cnt4(const int* __restrict__ cnt, int i, int N) {
    if (i + 3 < N) return *reinterpret_cast<const int4*>(cnt + i);
    int4 r;
    r.x = (i     < N) ? cnt[i]     : 0;
    r.y = (i + 1 < N) ? cnt[i + 1] : 0;
    r.z = (i + 2 < N) ? cnt[i + 2] : 0;
    r.w = (i + 3 < N) ? cnt[i + 3] : 0;
    return r;
}

// single-block scan over degrees -> row_ptr
__global__ void k_scan(const int* __restrict__ cnt, int* __restrict__ row_ptr, int N) {
    __shared__ int wsum[16];
    __shared__ int carry_s;
    __shared__ int tot_s;
    int t = threadIdx.x, lane = t & 63, wid = t >> 6;
    if (t == 0) { carry_s = 0; row_ptr[0] = 0; }
    __syncthreads();
    const int PER = 16, CHUNK = 1024 * PER;
    for (int base = 0; base < N; base += CHUNK) {
        int i0 = base + t * PER;
        int v[PER]; int s8 = 0;
#pragma unroll
        for (int k = 0; k < PER; k += 4) {
            int4 p = ld_cnt4(cnt, i0 + k, N);
            v[k] = p.x; v[k + 1] = p.y; v[k + 2] = p.z; v[k + 3] = p.w;
            s8 += p.x + p.y + p.z + p.w;
        }
        int incl = s8;
#pragma unroll
        for (int off = 1; off < 64; off <<= 1) {
            int n2 = __shfl_up(incl, off);
            if (lane >= off) incl += n2;
        }
        if (lane == 63) wsum[wid] = incl;
        __syncthreads();
        if (wid == 0) {
            int wv = (lane < 16) ? wsum[lane] : 0;
            int wincl = wv;
#pragma unroll
            for (int off = 1; off < 16; off <<= 1) {
                int n2 = __shfl_up(wincl, off);
                if (lane >= off) wincl += n2;
            }
            if (lane < 16) wsum[lane] = wincl - wv;
            if (lane == 15) tot_s = wincl;
        }
        __syncthreads();
        int run = carry_s + wsum[wid] + (incl - s8);
#pragma unroll
        for (int k = 0; k < PER; ++k) { int i = i0 + k; run += v[k]; if (i < N) row_ptr[i + 1] = run; }
        __syncthreads();
        if (t == 0) carry_s += tot_s;
        __syncthreads();
    }
}

// ---------------- tiny precompute: w2qk / bias ----------------
__global__ void k_tiny1(const float* __restrict__ trainOT, const float* __restrict__ Wq,
                        const float* __restrict__ bq, const float* __restrict__ Wk,
                        const float* __restrict__ bk, const float* __restrict__ W2,
                        const float* __restrict__ b2, float* __restrict__ small) {
    __shared__ float kv[64];
    __shared__ float wqk[128];
    __shared__ float red[128];
    int t = threadIdx.x;   // 128 threads
    if (t < 64) {
        float acc = bk[t];
        for (int j = 0; j < 128; ++j) acc += trainOT[j] * Wk[j * 64 + t];
        kv[t] = acc;
    }
    __syncthreads();
    float accq = 0.f;
    for (int c = 0; c < 64; ++c) accq += Wq[t * 64 + c] * kv[c];
    wqk[t] = accq;
    red[t] = (t < 64) ? bq[t] * kv[t] : 0.f;
    __syncthreads();
    for (int off = 64; off >= 1; off >>= 1) { if (t < off) red[t] += red[t + off]; __syncthreads(); }
    float bqs = red[0];
    __syncthreads();
    float acc2 = 0.f;
    for (int j = 0; j < 128; ++j) acc2 += W2[t * 128 + j] * wqk[j];
    small[t] = acc2;                       // w2qk
    red[t] = b2[t] * wqk[t];
    __syncthreads();
    for (int off = 64; off >= 1; off >>= 1) { if (t < off) red[t] += red[t + off]; __syncthreads(); }
    if (t == 0) small[128] = bqs + red[0]; // bias
}

// ---------------- layer 1: 16 lanes/node ----------------
__global__ void k_layer1(const float4* __restrict__ xs4, const int* __restrict__ row_ptr,
                         const int* __restrict__ col, const float* __restrict__ dinv,
                         const float* __restrict__ W1, const float* __restrict__ b1,
                         unsigned int* __restrict__ h1s, int N) {
    int t = threadIdx.x;
    int sub = t & 15;
    int node = blockIdx.x * 16 + (t >> 4);
    if (node >= N) return;
    float di = dinv[node];
    int s = row_ptr[node], e = row_ptr[node + 1];
    float a0 = 0.f, a1 = 0.f, a2 = 0.f;
    for (int j = s + sub; j < e; j += 16) {
        float4 xv = xs4[col[j]];
        a0 += xv.x; a1 += xv.y; a2 += xv.z;
    }
    if (sub == 0) { float4 xv = xs4[node]; a0 += xv.x; a1 += xv.y; a2 += xv.z; }
#pragma unroll
    for (int off = 1; off < 16; off <<= 1) {
        a0 += __shfl_xor(a0, off);
        a1 += __shfl_xor(a1, off);
        a2 += __shfl_xor(a2, off);
    }
    a0 *= di; a1 *= di; a2 *= di;
    unsigned int p[4];
#pragma unroll
    for (int m = 0; m < 4; ++m) {
        int c = 8 * sub + 2 * m;
        float vlo = fmaxf(a0 * W1[c]     + a1 * W1[128 + c]     + a2 * W1[256 + c]     + b1[c],     0.f) * di;
        float vhi = fmaxf(a0 * W1[c + 1] + a1 * W1[128 + c + 1] + a2 * W1[256 + c + 1] + b1[c + 1], 0.f) * di;
        p[m] = f2bf(vlo) | (f2bf(vhi) << 16);
    }
    uint4 st; st.x = p[0]; st.y = p[1]; st.z = p[2]; st.w = p[3];
    reinterpret_cast<uint4*>(h1s + (size_t)node * 64)[sub] = st;
}

// ---------------- layer 2 fused: quad-gather ----------------
__global__ void k_layer2(const unsigned int* __restrict__ h1s, const int* __restrict__ row_ptr,
                         const int* __restrict__ col, const float* __restrict__ dinv,
                         const float* __restrict__ small, float* __restrict__ part, int N) {
    int t = threadIdx.x, lane = t & 63, wid = t >> 6;
    int sub = lane & 15, grp = lane >> 4;
    int wg = blockIdx.x * 4 + wid;
    const int nwaves = LAYER2_BLOCKS * 4;
    float w2[8];
#pragma unroll
    for (int j = 0; j < 8; ++j) w2[j] = small[8 * sub + j];
    float bias = small[128];
    float sacc[8];
#pragma unroll
    for (int j = 0; j < 8; ++j) sacc[j] = 0.f;
    float sR = 0.f;

    for (int node = wg; node < N; node += nwaves) {
        float di = dinv[node];
        int s = row_ptr[node], e = row_ptr[node + 1];
        int items = e - s + 1;                    // self + edges
        float acc[8];
#pragma unroll
        for (int j = 0; j < 8; ++j) acc[j] = 0.f;
        for (int base = 0; base < items; base += 8) {
            int q0 = base + grp, q1 = base + 4 + grp;
            int u0 = (q0 == 0) ? node : ((q0 < items) ? col[s + q0 - 1] : N);
            int u1 = (q1 < items) ? col[s + q1 - 1] : N;
            uint4 v0 = reinterpret_cast<const uint4*>(h1s + (size_t)u0 * 64)[sub];
            uint4 v1 = reinterpret_cast<const uint4*>(h1s + (size_t)u1 * 64)[sub];
            acc[0] += bf_lo(v0.x) + bf_lo(v1.x);
            acc[1] += bf_hi(v0.x) + bf_hi(v1.x);
            acc[2] += bf_lo(v0.y) + bf_lo(v1.y);
            acc[3] += bf_hi(v0.y) + bf_hi(v1.y);
            acc[4] += bf_lo(v0.z) + bf_lo(v1.z);
            acc[5] += bf_hi(v0.z) + bf_hi(v1.z);
            acc[6] += bf_lo(v0.w) + bf_lo(v1.w);
            acc[7] += bf_hi(v0.w) + bf_hi(v1.w);
        }
#pragma unroll
        for (int j = 0; j < 8; ++j) {
            acc[j] += __shfl_xor(acc[j], 16);
            acc[j] += __shfl_xor(acc[j], 32);
        }
        float dv = 0.f;
#pragma unroll
        for (int j = 0; j < 8; ++j) dv += acc[j] * w2[j];
#pragma unroll
        for (int off = 1; off < 16; off <<= 1) dv += __shfl_xor(dv, off);
        float z = (dv * di + bias) * 0.125f;
        float rel = 1.f / (1.f + __expf(-z));
        float rd = rel * di;
#pragma unroll
        for (int j = 0; j < 8; ++j) sacc[j] += rd * acc[j];
        sR += rel;
    }
    __shared__ float sS[4][132];
    if (grp == 0) {
#pragma unroll
        for (int j = 0; j < 8; ++j) sS[wid][8 * sub + j] = sacc[j];
    }
    if (lane == 0) sS[wid][128] = sR;
    __syncthreads();
    if (t < 129) part[blockIdx.x * 132 + t] = sS[0][t] + sS[1][t] + sS[2][t] + sS[3][t];
}

__global__ void k_reduce_part(const float* __restrict__ part, int nblocks, float* __restrict__ small) {
    int c = blockIdx.x;   // 0..128
    float acc = 0.f;
    for (int b = threadIdx.x; b < nblocks; b += blockDim.x) acc += part[b * 132 + c];
    __shared__ float sd[256];
    sd[threadIdx.x] = acc; __syncthreads();
    for (int off = 128; off; off >>= 1) { if (threadIdx.x < off) sd[threadIdx.x] += sd[threadIdx.x + off]; __syncthreads(); }
    if (threadIdx.x == 0) small[132 + c] = sd[0];
}

// ---------------- newT = trainOT + (S@W2 + R*b2)@Wv + R*bv ----------------
__global__ void k_tiny2(const float* __restrict__ trainOT, const float* __restrict__ W2,
                        const float* __restrict__ b2, const float* __restrict__ Wv,
                        const float* __restrict__ bv, float* __restrict__ small,
                        float* __restrict__ out_tail) {
    __shared__ float t1[128];
    int t = threadIdx.x;   // 128
    float R = small[260];
    float acc = R * b2[t];
    for (int j = 0; j < 128; ++j) acc += small[132 + j] * W2[j * 128 + t];
    t1[t] = acc; __syncthreads();
    float acc2 = R * bv[t];
    for (int j = 0; j < 128; ++j) acc2 += t1[j] * Wv[j * 128 + t];
    float nt = trainOT[t] + acc2;
    small[264 + t] = nt;
    out_tail[t] = nt;
}

// ---------------- speak: out += nt @ Ws, K split 4-way, out pre-inited to bs ----------------
__global__ void k_tail(const float* __restrict__ Ws, const float* __restrict__ small,
                       float* __restrict__ out, int out_n) {
    int ks = blockIdx.x & 3;
    int j = ((blockIdx.x >> 2) << 8) + threadIdx.x;
    if (j >= out_n) return;
    const float* w = Ws + (size_t)(ks * 32) * out_n + j;
    const float* nt = small + 264 + ks * 32;
    float acc = 0.f;
#pragma unroll 8
    for (int k = 0; k < 32; ++k) acc += nt[k] * w[(size_t)k * out_n];
    atomicAdd(&out[j], acc);
}

extern "C" void kernel_launch(void* const* d_in, const int* in_sizes, int n_in,
                              void* d_out, int out_size, void* d_ws, size_t ws_size,
                              hipStream_t stream) {
    const float* features = (const float*)d_in[0];
    const int*   eidx     = (const int*)d_in[1];
    const float* trainOT  = (const float*)d_in[2];
    const float* W1 = (const float*)d_in[3];
    const float* b1 = (const float*)d_in[4];
    const float* W2 = (const float*)d_in[5];
    const float* b2 = (const float*)d_in[6];
    const float* Wq = (const float*)d_in[7];
    const float* bq = (const float*)d_in[8];
    const float* Wk = (const float*)d_in[9];
    const float* bk = (const float*)d_in[10];
    const float* Wv = (const float*)d_in[11];
    const float* bv = (const float*)d_in[12];
    const float* Ws = (const float*)d_in[13];
    const float* bs = (const float*)d_in[14];

    int N = in_sizes[0] / 3;
    int E = in_sizes[1] / 2;
    const int* esrc = eidx;
    const int* edst = eidx + E;
    int NB = (N + 255) >> 8;
    int CS = (E + NCHUNK - 1) / NCHUNK;

    char* ws = (char*)d_ws;
    int*   cnt     = (int*)(ws + O_CNT);
    int*   row_ptr = (int*)(ws + O_ROWPTR);
    float* dinv    = (float*)(ws + O_DINV);
    float* small   = (float*)(ws + O_SMALL);
    int*   ghist   = (int*)(ws + O_GHIST);
    int*   goff    = (int*)(ws + O_GOFF);
    unsigned int* sorted = (unsigned int*)(ws + O_SORT);
    float* part    = (float*)(ws + O_PART);
    float4* xs4    = (float4*)(ws + O_XS);
    int*   col     = (int*)(ws + O_COL);
    unsigned int* h1s = (unsigned int*)(ws + O_H1);
    float* out     = (float*)d_out;
    int out_n = out_size - 128;

    hipMemsetAsync(cnt, 0, N * sizeof(int), stream);

    k_tiny1<<<1, 128, 0, stream>>>(trainOT, Wq, bq, Wk, bk, W2, b2, small);
    k_hist<<<NCHUNK, 256, 0, stream>>>(edst, cnt, ghist, E, CS, NB);
    k_prep<<<(N + 255) / 256, 256, 0, stream>>>(cnt, features, bs, out, dinv, xs4, h1s, N);
    k_scan<<<1, 1024, 0, stream>>>(cnt, row_ptr, N);
    k_hscan<<<1, 1024, 0, stream>>>(ghist, goff, NB);
    k_scatter<<<NCHUNK, 256, 0, stream>>>(esrc, edst, goff, sorted, E, CS, NB);
    k_fill2<<<NB, 256, 0, stream>>>(sorted, goff, row_ptr, col, E, NB);
    k_layer1<<<(N + 15) / 16, 256, 0, stream>>>(xs4, row_ptr, col, dinv, W1, b1, h1s, N);
    k_layer2<<<LAYER2_BLOCKS, 256, 0, stream>>>(h1s, row_ptr, col, dinv, small, part, N);
    k_reduce_part<<<129, 256, 0, stream>>>(part, LAYER2_BLOCKS, small);
    k_tiny2<<<1, 128, 0, stream>>>(trainOT, W2, b2, Wv, bv, small, out + out_n);
    k_tail<<<((out_n + 255) / 256) * 4, 256, 0, stream>>>(Ws, small, out, out_n);
}

// Round 5
// 147.704 us; speedup vs baseline: 1.4722x; 1.4722x over previous
//
#include <hip/hip_runtime.h>
#include <math.h>

// ---------------- workspace layout (bytes) ----------------
#define O_CNT    (0)                  // N ints (200KB)
#define O_ROWPTR (256*1024)           // NB*256+ ints (~200KB)
#define O_DINV   (512*1024)           // N floats
#define O_SMALL  (768*1024)           // few KB
#define O_GHIST  (1024*1024)          // NB*256 ints (~200KB, [bucket][chunk])
#define O_BTOT   (1248*1024)          // NB ints
#define O_BSTART (1256*1024)          // NB+1 ints
#define O_GOFF   (1280*1024)          // NB*256 ints (~200KB, [bucket][chunk])
#define O_SORT   (1536*1024)          // E uints = 3.2MB (aliased: PART after fill2)
#define O_PART   (1536*1024)          // 2048*132*4 = 1.08MB (alias of SORT)
#define O_XS     (4800*1024)          // N float4 = 800KB
#define O_COL    (5760*1024)          // E ints = 3.2MB
#define O_H1     (9216*1024)          // (N+1)*64 uints = 12.8MB + zero row
// small[] float indices:
//   [0..127] w2qk  [128] bias  [132..259] S  [260] R  [264..391] new_trainOT

#define LAYER2_BLOCKS 2048
#define NCHUNK 256

static __device__ __forceinline__ unsigned int f2bf(float f) {
    unsigned int u = __float_as_uint(f);
    return (u + 0x7fffu + ((u >> 16) & 1u)) >> 16;            // RNE
}
static __device__ __forceinline__ float bf_lo(unsigned int w) { return __uint_as_float(w << 16); }
static __device__ __forceinline__ float bf_hi(unsigned int w) { return __uint_as_float(w & 0xffff0000u); }

// 256-thread exclusive block scan (4 waves). lds must hold >=4 ints.
static __device__ __forceinline__ int blockExclScan256(int v, volatile int* lds, int t) {
    int lane = t & 63, wid = t >> 6;
    int incl = v;
#pragma unroll
    for (int off = 1; off < 64; off <<= 1) {
        int n = __shfl_up(incl, off);
        if (lane >= off) incl += n;
    }
    if (lane == 63) lds[wid] = incl;
    __syncthreads();
    if (t == 0) {
        int s = 0;
#pragma unroll
        for (int i = 0; i < 4; ++i) { int x = lds[i]; lds[i] = s; s += x; }
    }
    __syncthreads();
    return lds[wid] + incl - v;
}

// ---------------- A1: per-chunk bucket histogram + degree count + bucket totals ----------------
__global__ void k_hist(const int* __restrict__ dst, int* __restrict__ cnt,
                       int* __restrict__ ghist, int* __restrict__ btot,
                       int E, int CS, int NB) {
    __shared__ int lh[256];
    int b = blockIdx.x, t = threadIdx.x;
    lh[t] = 0; __syncthreads();
    int s = b * CS, e = min(E, s + CS);
    for (int i = s + t; i < e; i += 256) {
        int d = dst[i];
        atomicAdd(&cnt[d], 1);          // in-degree
        atomicAdd(&lh[d >> 8], 1);      // bucket histogram (LDS)
    }
    __syncthreads();
    if (t < NB) {
        ghist[t * NCHUNK + b] = lh[t];  // transposed: [bucket][chunk]
        if (lh[t]) atomicAdd(&btot[t], lh[t]);
    }
}

// ---------------- A2: scan of 196 bucket totals (tiny) ----------------
__global__ void k_bstart(const int* __restrict__ btot, int* __restrict__ bstart, int NB) {
    __shared__ int lds[4];
    int t = threadIdx.x;   // 256
    int v = (t < NB) ? btot[t] : 0;
    int ex = blockExclScan256(v, lds, t);
    if (t <= NB) bstart[t] = ex;
}

// ---------------- A3: per-bucket chunk offsets AND node row_ptr (196 blocks) ----------------
__global__ void k_offsets(const int* __restrict__ ghist, const int* __restrict__ cnt,
                          const int* __restrict__ bstart, int* __restrict__ goff,
                          int* __restrict__ row_ptr, int N, int NB) {
    __shared__ int lds1[4];
    __shared__ int lds2[4];
    int nb = blockIdx.x, t = threadIdx.x;
    int base = bstart[nb];
    // chunk offsets within bucket
    int g = ghist[nb * NCHUNK + t];
    int gx = blockExclScan256(g, lds1, t);
    goff[nb * NCHUNK + t] = base + gx;
    // node row_ptr within bucket
    int i = (nb << 8) + t;
    int c = (i < N) ? cnt[i] : 0;
    int cx = blockExclScan256(c, lds2, t);
    row_ptr[i] = base + cx;             // for i >= N this writes E (harmless, in-bounds)
}

// ---------------- A4: scatter edges into bucket-sorted runs ----------------
__global__ void k_scatter(const int* __restrict__ src, const int* __restrict__ dst,
                          const int* __restrict__ goff, unsigned int* __restrict__ sorted,
                          int E, int CS, int NB) {
    __shared__ int lcur[256];
    int b = blockIdx.x, t = threadIdx.x;
    if (t < NB) lcur[t] = goff[t * NCHUNK + b];
    __syncthreads();
    int s = b * CS, e = min(E, s + CS);
    for (int i = s + t; i < e; i += 256) {
        int d = dst[i];
        int pos = atomicAdd(&lcur[d >> 8], 1);
        sorted[pos] = ((unsigned int)(d & 255) << 16) | (unsigned int)src[i];   // N <= 65536
    }
}

// ---------------- B: per-bucket regroup into final CSR (localized writes) ----------------
__global__ void k_fill2(const unsigned int* __restrict__ sorted, const int* __restrict__ bstart,
                        const int* __restrict__ row_ptr, int* __restrict__ col, int E, int NB) {
    __shared__ int lcnt[256];
    int nb = blockIdx.x, t = threadIdx.x;
    lcnt[t] = 0; __syncthreads();
    int s = bstart[nb];
    int e = bstart[nb + 1];
    int dbase = nb << 8;
    for (int i = s + t; i < e; i += 256) {
        unsigned int v = sorted[i];
        int dl = v >> 16;
        int p = row_ptr[dbase + dl] + atomicAdd(&lcnt[dl], 1);
        col[p] = (int)(v & 0xffffu);
    }
}

// dinv + pre-scaled packed features + zero h1 row + out = bs init
__global__ void k_prep(const int* __restrict__ cnt, const float* __restrict__ x,
                       const float* __restrict__ bs, float* __restrict__ out,
                       float* __restrict__ dinv, float4* __restrict__ xs4,
                       unsigned int* __restrict__ h1s, int N) {
    int i = blockIdx.x * blockDim.x + threadIdx.x;
    if (i < N) {
        float d = rsqrtf((float)(cnt[i] + 1));   // +1 self-loop
        dinv[i] = d;
        float4 v;
        v.x = x[i * 3] * d; v.y = x[i * 3 + 1] * d; v.z = x[i * 3 + 2] * d; v.w = 0.f;
        xs4[i] = v;
        reinterpret_cast<float2*>(out)[i] = reinterpret_cast<const float2*>(bs)[i];  // out_n == 2N
    }
    if (i < 64) h1s[(size_t)N * 64 + i] = 0u;    // zero row for ragged-tail gathers
}

// ---------------- tiny precompute: w2qk / bias ----------------
__global__ void k_tiny1(const float* __restrict__ trainOT, const float* __restrict__ Wq,
                        const float* __restrict__ bq, const float* __restrict__ Wk,
                        const float* __restrict__ bk, const float* __restrict__ W2,
                        const float* __restrict__ b2, float* __restrict__ small) {
    __shared__ float kv[64];
    __shared__ float wqk[128];
    __shared__ float red[128];
    int t = threadIdx.x;   // 128 threads
    if (t < 64) {
        float acc = bk[t];
        for (int j = 0; j < 128; ++j) acc += trainOT[j] * Wk[j * 64 + t];
        kv[t] = acc;
    }
    __syncthreads();
    float accq = 0.f;
    for (int c = 0; c < 64; ++c) accq += Wq[t * 64 + c] * kv[c];
    wqk[t] = accq;
    red[t] = (t < 64) ? bq[t] * kv[t] : 0.f;
    __syncthreads();
    for (int off = 64; off >= 1; off >>= 1) { if (t < off) red[t] += red[t + off]; __syncthreads(); }
    float bqs = red[0];
    __syncthreads();
    float acc2 = 0.f;
    for (int j = 0; j < 128; ++j) acc2 += W2[t * 128 + j] * wqk[j];
    small[t] = acc2;                       // w2qk
    red[t] = b2[t] * wqk[t];
    __syncthreads();
    for (int off = 64; off >= 1; off >>= 1) { if (t < off) red[t] += red[t + off]; __syncthreads(); }
    if (t == 0) small[128] = bqs + red[0]; // bias
}

// ---------------- layer 1: 16 lanes/node ----------------
__global__ void k_layer1(const float4* __restrict__ xs4, const int* __restrict__ row_ptr,
                         const int* __restrict__ col, const float* __restrict__ dinv,
                         const float* __restrict__ W1, const float* __restrict__ b1,
                         unsigned int* __restrict__ h1s, int N) {
    int t = threadIdx.x;
    int sub = t & 15;
    int node = blockIdx.x * 16 + (t >> 4);
    if (node >= N) return;
    float di = dinv[node];
    int s = row_ptr[node], e = row_ptr[node + 1];
    float a0 = 0.f, a1 = 0.f, a2 = 0.f;
    for (int j = s + sub; j < e; j += 16) {
        float4 xv = xs4[col[j]];
        a0 += xv.x; a1 += xv.y; a2 += xv.z;
    }
    if (sub == 0) { float4 xv = xs4[node]; a0 += xv.x; a1 += xv.y; a2 += xv.z; }
#pragma unroll
    for (int off = 1; off < 16; off <<= 1) {
        a0 += __shfl_xor(a0, off);
        a1 += __shfl_xor(a1, off);
        a2 += __shfl_xor(a2, off);
    }
    a0 *= di; a1 *= di; a2 *= di;
    unsigned int p[4];
#pragma unroll
    for (int m = 0; m < 4; ++m) {
        int c = 8 * sub + 2 * m;
        float vlo = fmaxf(a0 * W1[c]     + a1 * W1[128 + c]     + a2 * W1[256 + c]     + b1[c],     0.f) * di;
        float vhi = fmaxf(a0 * W1[c + 1] + a1 * W1[128 + c + 1] + a2 * W1[256 + c + 1] + b1[c + 1], 0.f) * di;
        p[m] = f2bf(vlo) | (f2bf(vhi) << 16);
    }
    uint4 st; st.x = p[0]; st.y = p[1]; st.z = p[2]; st.w = p[3];
    reinterpret_cast<uint4*>(h1s + (size_t)node * 64)[sub] = st;
}

// ---------------- layer 2 fused: quad-gather ----------------
__global__ void k_layer2(const unsigned int* __restrict__ h1s, const int* __restrict__ row_ptr,
                         const int* __restrict__ col, const float* __restrict__ dinv,
                         const float* __restrict__ small, float* __restrict__ part, int N) {
    int t = threadIdx.x, lane = t & 63, wid = t >> 6;
    int sub = lane & 15, grp = lane >> 4;
    int wg = blockIdx.x * 4 + wid;
    const int nwaves = LAYER2_BLOCKS * 4;
    float w2[8];
#pragma unroll
    for (int j = 0; j < 8; ++j) w2[j] = small[8 * sub + j];
    float bias = small[128];
    float sacc[8];
#pragma unroll
    for (int j = 0; j < 8; ++j) sacc[j] = 0.f;
    float sR = 0.f;

    for (int node = wg; node < N; node += nwaves) {
        float di = dinv[node];
        int s = row_ptr[node], e = row_ptr[node + 1];
        int items = e - s + 1;                    // self + edges
        float acc[8];
#pragma unroll
        for (int j = 0; j < 8; ++j) acc[j] = 0.f;
        for (int base = 0; base < items; base += 8) {
            int q0 = base + grp, q1 = base + 4 + grp;
            int u0 = (q0 == 0) ? node : ((q0 < items) ? col[s + q0 - 1] : N);
            int u1 = (q1 < items) ? col[s + q1 - 1] : N;
            uint4 v0 = reinterpret_cast<const uint4*>(h1s + (size_t)u0 * 64)[sub];
            uint4 v1 = reinterpret_cast<const uint4*>(h1s + (size_t)u1 * 64)[sub];
            acc[0] += bf_lo(v0.x) + bf_lo(v1.x);
            acc[1] += bf_hi(v0.x) + bf_hi(v1.x);
            acc[2] += bf_lo(v0.y) + bf_lo(v1.y);
            acc[3] += bf_hi(v0.y) + bf_hi(v1.y);
            acc[4] += bf_lo(v0.z) + bf_lo(v1.z);
            acc[5] += bf_hi(v0.z) + bf_hi(v1.z);
            acc[6] += bf_lo(v0.w) + bf_lo(v1.w);
            acc[7] += bf_hi(v0.w) + bf_hi(v1.w);
        }
#pragma unroll
        for (int j = 0; j < 8; ++j) {
            acc[j] += __shfl_xor(acc[j], 16);
            acc[j] += __shfl_xor(acc[j], 32);
        }
        float dv = 0.f;
#pragma unroll
        for (int j = 0; j < 8; ++j) dv += acc[j] * w2[j];
#pragma unroll
        for (int off = 1; off < 16; off <<= 1) dv += __shfl_xor(dv, off);
        float z = (dv * di + bias) * 0.125f;
        float rel = 1.f / (1.f + __expf(-z));
        float rd = rel * di;
#pragma unroll
        for (int j = 0; j < 8; ++j) sacc[j] += rd * acc[j];
        sR += rel;
    }
    __shared__ float sS[4][132];
    if (grp == 0) {
#pragma unroll
        for (int j = 0; j < 8; ++j) sS[wid][8 * sub + j] = sacc[j];
    }
    if (lane == 0) sS[wid][128] = sR;
    __syncthreads();
    if (t < 129) part[blockIdx.x * 132 + t] = sS[0][t] + sS[1][t] + sS[2][t] + sS[3][t];
}

__global__ void k_reduce_part(const float* __restrict__ part, int nblocks, float* __restrict__ small) {
    int c = blockIdx.x;   // 0..128
    float acc = 0.f;
    for (int b = threadIdx.x; b < nblocks; b += blockDim.x) acc += part[b * 132 + c];
    __shared__ float sd[256];
    sd[threadIdx.x] = acc; __syncthreads();
    for (int off = 128; off; off >>= 1) { if (threadIdx.x < off) sd[threadIdx.x] += sd[threadIdx.x + off]; __syncthreads(); }
    if (threadIdx.x == 0) small[132 + c] = sd[0];
}

// ---------------- newT = trainOT + (S@W2 + R*b2)@Wv + R*bv ----------------
__global__ void k_tiny2(const float* __restrict__ trainOT, const float* __restrict__ W2,
                        const float* __restrict__ b2, const float* __restrict__ Wv,
                        const float* __restrict__ bv, float* __restrict__ small,
                        float* __restrict__ out_tail) {
    __shared__ float t1[128];
    int t = threadIdx.x;   // 128
    float R = small[260];
    float acc = R * b2[t];
    for (int j = 0; j < 128; ++j) acc += small[132 + j] * W2[j * 128 + t];
    t1[t] = acc; __syncthreads();
    float acc2 = R * bv[t];
    for (int j = 0; j < 128; ++j) acc2 += t1[j] * Wv[j * 128 + t];
    float nt = trainOT[t] + acc2;
    small[264 + t] = nt;
    out_tail[t] = nt;
}

// ---------------- speak: out += nt @ Ws, K split 4-way, out pre-inited to bs ----------------
__global__ void k_tail(const float* __restrict__ Ws, const float* __restrict__ small,
                       float* __restrict__ out, int out_n) {
    int ks = blockIdx.x & 3;
    int j = ((blockIdx.x >> 2) << 8) + threadIdx.x;
    if (j >= out_n) return;
    const float* w = Ws + (size_t)(ks * 32) * out_n + j;
    const float* nt = small + 264 + ks * 32;
    float acc = 0.f;
#pragma unroll 8
    for (int k = 0; k < 32; ++k) acc += nt[k] * w[(size_t)k * out_n];
    atomicAdd(&out[j], acc);
}

extern "C" void kernel_launch(void* const* d_in, const int* in_sizes, int n_in,
                              void* d_out, int out_size, void* d_ws, size_t ws_size,
                              hipStream_t stream) {
    const float* features = (const float*)d_in[0];
    const int*   eidx     = (const int*)d_in[1];
    const float* trainOT  = (const float*)d_in[2];
    const float* W1 = (const float*)d_in[3];
    const float* b1 = (const float*)d_in[4];
    const float* W2 = (const float*)d_in[5];
    const float* b2 = (const float*)d_in[6];
    const float* Wq = (const float*)d_in[7];
    const float* bq = (const float*)d_in[8];
    const float* Wk = (const float*)d_in[9];
    const float* bk = (const float*)d_in[10];
    const float* Wv = (const float*)d_in[11];
    const float* bv = (const float*)d_in[12];
    const float* Ws = (const float*)d_in[13];
    const float* bs = (const float*)d_in[14];

    int N = in_sizes[0] / 3;
    int E = in_sizes[1] / 2;
    const int* esrc = eidx;
    const int* edst = eidx + E;
    int NB = (N + 255) >> 8;
    int CS = (E + NCHUNK - 1) / NCHUNK;

    char* ws = (char*)d_ws;
    int*   cnt     = (int*)(ws + O_CNT);
    int*   row_ptr = (int*)(ws + O_ROWPTR);
    float* dinv    = (float*)(ws + O_DINV);
    float* small   = (float*)(ws + O_SMALL);
    int*   ghist   = (int*)(ws + O_GHIST);
    int*   btot    = (int*)(ws + O_BTOT);
    int*   bstart  = (int*)(ws + O_BSTART);
    int*   goff    = (int*)(ws + O_GOFF);
    unsigned int* sorted = (unsigned int*)(ws + O_SORT);
    float* part    = (float*)(ws + O_PART);
    float4* xs4    = (float4*)(ws + O_XS);
    int*   col     = (int*)(ws + O_COL);
    unsigned int* h1s = (unsigned int*)(ws + O_H1);
    float* out     = (float*)d_out;
    int out_n = out_size - 128;

    hipMemsetAsync(cnt, 0, N * sizeof(int), stream);
    hipMemsetAsync(btot, 0, 1024, stream);

    k_tiny1<<<1, 128, 0, stream>>>(trainOT, Wq, bq, Wk, bk, W2, b2, small);
    k_hist<<<NCHUNK, 256, 0, stream>>>(edst, cnt, ghist, btot, E, CS, NB);
    k_prep<<<(N + 255) / 256, 256, 0, stream>>>(cnt, features, bs, out, dinv, xs4, h1s, N);
    k_bstart<<<1, 256, 0, stream>>>(btot, bstart, NB);
    k_offsets<<<NB, 256, 0, stream>>>(ghist, cnt, bstart, goff, row_ptr, N, NB);
    k_scatter<<<NCHUNK, 256, 0, stream>>>(esrc, edst, goff, sorted, E, CS, NB);
    k_fill2<<<NB, 256, 0, stream>>>(sorted, bstart, row_ptr, col, E, NB);
    k_layer1<<<(N + 15) / 16, 256, 0, stream>>>(xs4, row_ptr, col, dinv, W1, b1, h1s, N);
    k_layer2<<<LAYER2_BLOCKS, 256, 0, stream>>>(h1s, row_ptr, col, dinv, small, part, N);
    k_reduce_part<<<129, 256, 0, stream>>>(part, LAYER2_BLOCKS, small);
    k_tiny2<<<1, 128, 0, stream>>>(trainOT, W2, b2, Wv, bv, small, out + out_n);
    k_tail<<<((out_n + 255) / 256) * 4, 256, 0, stream>>>(Ws, small, out, out_n);
}

// Round 6
// 115.578 us; speedup vs baseline: 1.8814x; 1.2780x over previous
//
#include <hip/hip_runtime.h>
#include <math.h>

// ---------------- workspace layout (bytes) ----------------
#define O_ROWPTR (256*1024)           // NB*256+ ints (~200KB)
#define O_DINV   (512*1024)           // N floats
#define O_SMALL  (768*1024)           // few KB
#define O_GHIST  (1024*1024)          // NB*256 ints (~200KB, [bucket][chunk])
#define O_BSTART (1256*1024)          // NB+1 ints
#define O_GOFF   (1280*1024)          // NB*256 ints (~200KB, [bucket][chunk])
#define O_SORT   (1536*1024)          // E uints = 3.2MB (aliased: PART after build)
#define O_PART   (1536*1024)          // 2048*132*4 = 1.08MB (alias of SORT)
#define O_XS     (4800*1024)          // N float4 = 800KB
#define O_COL    (5760*1024)          // E ints = 3.2MB
#define O_H1     (9216*1024)          // (N+1)*64 uints = 12.8MB + zero row
// small[] float indices:
//   [0..127] w2qk  [128] bias  [132..259] S  [260] R  [264..391] new_trainOT

#define LAYER2_BLOCKS 2048
#define NCHUNK 256

static __device__ __forceinline__ unsigned int f2bf(float f) {
    unsigned int u = __float_as_uint(f);
    return (u + 0x7fffu + ((u >> 16) & 1u)) >> 16;            // RNE
}
static __device__ __forceinline__ float bf_lo(unsigned int w) { return __uint_as_float(w << 16); }
static __device__ __forceinline__ float bf_hi(unsigned int w) { return __uint_as_float(w & 0xffff0000u); }

// 256-thread exclusive block scan (4 waves). lds must hold >=4 ints.
static __device__ __forceinline__ int blockExclScan256(int v, volatile int* lds, int t) {
    int lane = t & 63, wid = t >> 6;
    int incl = v;
#pragma unroll
    for (int off = 1; off < 64; off <<= 1) {
        int n = __shfl_up(incl, off);
        if (lane >= off) incl += n;
    }
    if (lane == 63) lds[wid] = incl;
    __syncthreads();
    if (t == 0) {
        int s = 0;
#pragma unroll
        for (int i = 0; i < 4; ++i) { int x = lds[i]; lds[i] = s; s += x; }
    }
    __syncthreads();
    return lds[wid] + incl - v;
}

// ---------------- A1: per-chunk bucket histogram (LDS only, no global atomics) ----------------
__global__ void k_hist(const int* __restrict__ dst, int* __restrict__ ghist,
                       int E, int CS, int NB) {
    __shared__ int lh[256];
    int b = blockIdx.x, t = threadIdx.x;
    lh[t] = 0; __syncthreads();
    int s = b * CS, e = min(E, s + CS);
    for (int i = s + t; i < e; i += 256) {
        atomicAdd(&lh[dst[i] >> 8], 1);
    }
    __syncthreads();
    if (t < NB) ghist[t * NCHUNK + b] = lh[t];   // transposed: [bucket][chunk]
}

// ---------------- A2: bucket totals (row-sum of ghist) + scan of NB totals ----------------
__global__ void k_bstart(const int* __restrict__ ghist, int* __restrict__ bstart, int NB) {
    __shared__ int lds[4];
    int t = threadIdx.x;   // 256
    int v = 0;
    if (t < NB) {
        const int* row = ghist + t * NCHUNK;
        for (int b = 0; b < NCHUNK; ++b) v += row[b];
    }
    int ex = blockExclScan256(v, lds, t);
    if (t <= NB) bstart[t] = ex;
}

// ---------------- A3: per-bucket chunk offsets (NB blocks) ----------------
__global__ void k_goff(const int* __restrict__ ghist, const int* __restrict__ bstart,
                       int* __restrict__ goff, int NB) {
    __shared__ int lds1[4];
    int nb = blockIdx.x, t = threadIdx.x;
    int base = bstart[nb];
    int g = ghist[nb * NCHUNK + t];
    int gx = blockExclScan256(g, lds1, t);
    goff[nb * NCHUNK + t] = base + gx;
}

// ---------------- A4: scatter edges into bucket-sorted runs ----------------
__global__ void k_scatter(const int* __restrict__ src, const int* __restrict__ dst,
                          const int* __restrict__ goff, unsigned int* __restrict__ sorted,
                          int E, int CS, int NB) {
    __shared__ int lcur[256];
    int b = blockIdx.x, t = threadIdx.x;
    if (t < NB) lcur[t] = goff[t * NCHUNK + b];
    __syncthreads();
    int s = b * CS, e = min(E, s + CS);
    for (int i = s + t; i < e; i += 256) {
        int d = dst[i];
        int pos = atomicAdd(&lcur[d >> 8], 1);
        sorted[pos] = ((unsigned int)(d & 255) << 16) | (unsigned int)src[i];   // N <= 65536
    }
}

// ---------------- B: per-bucket degree count + row_ptr + dinv + CSR fill (no global atomics) ----
__global__ void k_build(const unsigned int* __restrict__ sorted, const int* __restrict__ bstart,
                        int* __restrict__ row_ptr, int* __restrict__ col,
                        float* __restrict__ dinv, int N, int NB) {
    __shared__ int lcnt[256];
    __shared__ int lpos[256];
    __shared__ int lds1[4];
    int nb = blockIdx.x, t = threadIdx.x;
    lcnt[t] = 0; __syncthreads();
    int s = bstart[nb], e = bstart[nb + 1];
    // pass 1: per-node degree within bucket
    for (int i = s + t; i < e; i += 256) {
        atomicAdd(&lcnt[sorted[i] >> 16], 1);
    }
    __syncthreads();
    int c = lcnt[t];
    int cx = blockExclScan256(c, lds1, t);
    int rp = s + cx;
    int node = (nb << 8) + t;
    row_ptr[node] = rp;                         // for node >= N this writes E (harmless)
    lpos[t] = rp;
    if (node < N) dinv[node] = rsqrtf((float)(c + 1));   // +1 self-loop
    __syncthreads();
    // pass 2: scatter into final CSR (bucket-local positions, LDS cursor)
    for (int i = s + t; i < e; i += 256) {
        unsigned int v = sorted[i];
        int p = atomicAdd(&lpos[v >> 16], 1);
        col[p] = (int)(v & 0xffffu);
    }
}

// pre-scaled packed features + zero h1 row + out = bs init
__global__ void k_prep(const float* __restrict__ dinv, const float* __restrict__ x,
                       const float* __restrict__ bs, float* __restrict__ out,
                       float4* __restrict__ xs4, unsigned int* __restrict__ h1s, int N) {
    int i = blockIdx.x * blockDim.x + threadIdx.x;
    if (i < N) {
        float d = dinv[i];
        float4 v;
        v.x = x[i * 3] * d; v.y = x[i * 3 + 1] * d; v.z = x[i * 3 + 2] * d; v.w = 0.f;
        xs4[i] = v;
        reinterpret_cast<float2*>(out)[i] = reinterpret_cast<const float2*>(bs)[i];  // out_n == 2N
    }
    if (i < 64) h1s[(size_t)N * 64 + i] = 0u;    // zero row for ragged-tail gathers
}

// ---------------- tiny precompute: w2qk / bias ----------------
__global__ void k_tiny1(const float* __restrict__ trainOT, const float* __restrict__ Wq,
                        const float* __restrict__ bq, const float* __restrict__ Wk,
                        const float* __restrict__ bk, const float* __restrict__ W2,
                        const float* __restrict__ b2, float* __restrict__ small) {
    __shared__ float kv[64];
    __shared__ float wqk[128];
    __shared__ float red[128];
    int t = threadIdx.x;   // 128 threads
    if (t < 64) {
        float acc = bk[t];
        for (int j = 0; j < 128; ++j) acc += trainOT[j] * Wk[j * 64 + t];
        kv[t] = acc;
    }
    __syncthreads();
    float accq = 0.f;
    for (int c = 0; c < 64; ++c) accq += Wq[t * 64 + c] * kv[c];
    wqk[t] = accq;
    red[t] = (t < 64) ? bq[t] * kv[t] : 0.f;
    __syncthreads();
    for (int off = 64; off >= 1; off >>= 1) { if (t < off) red[t] += red[t + off]; __syncthreads(); }
    float bqs = red[0];
    __syncthreads();
    float acc2 = 0.f;
    for (int j = 0; j < 128; ++j) acc2 += W2[t * 128 + j] * wqk[j];
    small[t] = acc2;                       // w2qk
    red[t] = b2[t] * wqk[t];
    __syncthreads();
    for (int off = 64; off >= 1; off >>= 1) { if (t < off) red[t] += red[t + off]; __syncthreads(); }
    if (t == 0) small[128] = bqs + red[0]; // bias
}

// ---------------- layer 1: 16 lanes/node ----------------
__global__ void k_layer1(const float4* __restrict__ xs4, const int* __restrict__ row_ptr,
                         const int* __restrict__ col, const float* __restrict__ dinv,
                         const float* __restrict__ W1, const float* __restrict__ b1,
                         unsigned int* __restrict__ h1s, int N) {
    int t = threadIdx.x;
    int sub = t & 15;
    int node = blockIdx.x * 16 + (t >> 4);
    if (node >= N) return;
    float di = dinv[node];
    int s = row_ptr[node], e = row_ptr[node + 1];
    float a0 = 0.f, a1 = 0.f, a2 = 0.f;
    for (int j = s + sub; j < e; j += 16) {
        float4 xv = xs4[col[j]];
        a0 += xv.x; a1 += xv.y; a2 += xv.z;
    }
    if (sub == 0) { float4 xv = xs4[node]; a0 += xv.x; a1 += xv.y; a2 += xv.z; }
#pragma unroll
    for (int off = 1; off < 16; off <<= 1) {
        a0 += __shfl_xor(a0, off);
        a1 += __shfl_xor(a1, off);
        a2 += __shfl_xor(a2, off);
    }
    a0 *= di; a1 *= di; a2 *= di;
    unsigned int p[4];
#pragma unroll
    for (int m = 0; m < 4; ++m) {
        int c = 8 * sub + 2 * m;
        float vlo = fmaxf(a0 * W1[c]     + a1 * W1[128 + c]     + a2 * W1[256 + c]     + b1[c],     0.f) * di;
        float vhi = fmaxf(a0 * W1[c + 1] + a1 * W1[128 + c + 1] + a2 * W1[256 + c + 1] + b1[c + 1], 0.f) * di;
        p[m] = f2bf(vlo) | (f2bf(vhi) << 16);
    }
    uint4 st; st.x = p[0]; st.y = p[1]; st.z = p[2]; st.w = p[3];
    reinterpret_cast<uint4*>(h1s + (size_t)node * 64)[sub] = st;
}

// ---------------- layer 2 fused: quad-gather ----------------
__global__ void k_layer2(const unsigned int* __restrict__ h1s, const int* __restrict__ row_ptr,
                         const int* __restrict__ col, const float* __restrict__ dinv,
                         const float* __restrict__ small, float* __restrict__ part, int N) {
    int t = threadIdx.x, lane = t & 63, wid = t >> 6;
    int sub = lane & 15, grp = lane >> 4;
    int wg = blockIdx.x * 4 + wid;
    const int nwaves = LAYER2_BLOCKS * 4;
    float w2[8];
#pragma unroll
    for (int j = 0; j < 8; ++j) w2[j] = small[8 * sub + j];
    float bias = small[128];
    float sacc[8];
#pragma unroll
    for (int j = 0; j < 8; ++j) sacc[j] = 0.f;
    float sR = 0.f;

    for (int node = wg; node < N; node += nwaves) {
        float di = dinv[node];
        int s = row_ptr[node], e = row_ptr[node + 1];
        int items = e - s + 1;                    // self + edges
        float acc[8];
#pragma unroll
        for (int j = 0; j < 8; ++j) acc[j] = 0.f;
        for (int base = 0; base < items; base += 8) {
            int q0 = base + grp, q1 = base + 4 + grp;
            int u0 = (q0 == 0) ? node : ((q0 < items) ? col[s + q0 - 1] : N);
            int u1 = (q1 < items) ? col[s + q1 - 1] : N;
            uint4 v0 = reinterpret_cast<const uint4*>(h1s + (size_t)u0 * 64)[sub];
            uint4 v1 = reinterpret_cast<const uint4*>(h1s + (size_t)u1 * 64)[sub];
            acc[0] += bf_lo(v0.x) + bf_lo(v1.x);
            acc[1] += bf_hi(v0.x) + bf_hi(v1.x);
            acc[2] += bf_lo(v0.y) + bf_lo(v1.y);
            acc[3] += bf_hi(v0.y) + bf_hi(v1.y);
            acc[4] += bf_lo(v0.z) + bf_lo(v1.z);
            acc[5] += bf_hi(v0.z) + bf_hi(v1.z);
            acc[6] += bf_lo(v0.w) + bf_lo(v1.w);
            acc[7] += bf_hi(v0.w) + bf_hi(v1.w);
        }
#pragma unroll
        for (int j = 0; j < 8; ++j) {
            acc[j] += __shfl_xor(acc[j], 16);
            acc[j] += __shfl_xor(acc[j], 32);
        }
        float dv = 0.f;
#pragma unroll
        for (int j = 0; j < 8; ++j) dv += acc[j] * w2[j];
#pragma unroll
        for (int off = 1; off < 16; off <<= 1) dv += __shfl_xor(dv, off);
        float z = (dv * di + bias) * 0.125f;
        float rel = 1.f / (1.f + __expf(-z));
        float rd = rel * di;
#pragma unroll
        for (int j = 0; j < 8; ++j) sacc[j] += rd * acc[j];
        sR += rel;
    }
    __shared__ float sS[4][132];
    if (grp == 0) {
#pragma unroll
        for (int j = 0; j < 8; ++j) sS[wid][8 * sub + j] = sacc[j];
    }
    if (lane == 0) sS[wid][128] = sR;
    __syncthreads();
    if (t < 129) part[blockIdx.x * 132 + t] = sS[0][t] + sS[1][t] + sS[2][t] + sS[3][t];
}

__global__ void k_reduce_part(const float* __restrict__ part, int nblocks, float* __restrict__ small) {
    int c = blockIdx.x;   // 0..128
    float acc = 0.f;
    for (int b = threadIdx.x; b < nblocks; b += blockDim.x) acc += part[b * 132 + c];
    __shared__ float sd[256];
    sd[threadIdx.x] = acc; __syncthreads();
    for (int off = 128; off; off >>= 1) { if (threadIdx.x < off) sd[threadIdx.x] += sd[threadIdx.x + off]; __syncthreads(); }
    if (threadIdx.x == 0) small[132 + c] = sd[0];
}

// ---------------- newT = trainOT + (S@W2 + R*b2)@Wv + R*bv ----------------
__global__ void k_tiny2(const float* __restrict__ trainOT, const float* __restrict__ W2,
                        const float* __restrict__ b2, const float* __restrict__ Wv,
                        const float* __restrict__ bv, float* __restrict__ small,
                        float* __restrict__ out_tail) {
    __shared__ float t1[128];
    int t = threadIdx.x;   // 128
    float R = small[260];
    float acc = R * b2[t];
    for (int j = 0; j < 128; ++j) acc += small[132 + j] * W2[j * 128 + t];
    t1[t] = acc; __syncthreads();
    float acc2 = R * bv[t];
    for (int j = 0; j < 128; ++j) acc2 += t1[j] * Wv[j * 128 + t];
    float nt = trainOT[t] + acc2;
    small[264 + t] = nt;
    out_tail[t] = nt;
}

// ---------------- speak: out += nt @ Ws, K split 4-way, out pre-inited to bs ----------------
__global__ void k_tail(const float* __restrict__ Ws, const float* __restrict__ small,
                       float* __restrict__ out, int out_n) {
    int ks = blockIdx.x & 3;
    int j = ((blockIdx.x >> 2) << 8) + threadIdx.x;
    if (j >= out_n) return;
    const float* w = Ws + (size_t)(ks * 32) * out_n + j;
    const float* nt = small + 264 + ks * 32;
    float acc = 0.f;
#pragma unroll 8
    for (int k = 0; k < 32; ++k) acc += nt[k] * w[(size_t)k * out_n];
    atomicAdd(&out[j], acc);
}

extern "C" void kernel_launch(void* const* d_in, const int* in_sizes, int n_in,
                              void* d_out, int out_size, void* d_ws, size_t ws_size,
                              hipStream_t stream) {
    const float* features = (const float*)d_in[0];
    const int*   eidx     = (const int*)d_in[1];
    const float* trainOT  = (const float*)d_in[2];
    const float* W1 = (const float*)d_in[3];
    const float* b1 = (const float*)d_in[4];
    const float* W2 = (const float*)d_in[5];
    const float* b2 = (const float*)d_in[6];
    const float* Wq = (const float*)d_in[7];
    const float* bq = (const float*)d_in[8];
    const float* Wk = (const float*)d_in[9];
    const float* bk = (const float*)d_in[10];
    const float* Wv = (const float*)d_in[11];
    const float* bv = (const float*)d_in[12];
    const float* Ws = (const float*)d_in[13];
    const float* bs = (const float*)d_in[14];

    int N = in_sizes[0] / 3;
    int E = in_sizes[1] / 2;
    const int* esrc = eidx;
    const int* edst = eidx + E;
    int NB = (N + 255) >> 8;
    int CS = (E + NCHUNK - 1) / NCHUNK;

    char* ws = (char*)d_ws;
    int*   row_ptr = (int*)(ws + O_ROWPTR);
    float* dinv    = (float*)(ws + O_DINV);
    float* small   = (float*)(ws + O_SMALL);
    int*   ghist   = (int*)(ws + O_GHIST);
    int*   bstart  = (int*)(ws + O_BSTART);
    int*   goff    = (int*)(ws + O_GOFF);
    unsigned int* sorted = (unsigned int*)(ws + O_SORT);
    float* part    = (float*)(ws + O_PART);
    float4* xs4    = (float4*)(ws + O_XS);
    int*   col     = (int*)(ws + O_COL);
    unsigned int* h1s = (unsigned int*)(ws + O_H1);
    float* out     = (float*)d_out;
    int out_n = out_size - 128;

    k_tiny1<<<1, 128, 0, stream>>>(trainOT, Wq, bq, Wk, bk, W2, b2, small);
    k_hist<<<NCHUNK, 256, 0, stream>>>(edst, ghist, E, CS, NB);
    k_bstart<<<1, 256, 0, stream>>>(ghist, bstart, NB);
    k_goff<<<NB, 256, 0, stream>>>(ghist, bstart, goff, NB);
    k_scatter<<<NCHUNK, 256, 0, stream>>>(esrc, edst, goff, sorted, E, CS, NB);
    k_build<<<NB, 256, 0, stream>>>(sorted, bstart, row_ptr, col, dinv, N, NB);
    k_prep<<<(N + 255) / 256, 256, 0, stream>>>(dinv, features, bs, out, xs4, h1s, N);
    k_layer1<<<(N + 15) / 16, 256, 0, stream>>>(xs4, row_ptr, col, dinv, W1, b1, h1s, N);
    k_layer2<<<LAYER2_BLOCKS, 256, 0, stream>>>(h1s, row_ptr, col, dinv, small, part, N);
    k_reduce_part<<<129, 256, 0, stream>>>(part, LAYER2_BLOCKS, small);
    k_tiny2<<<1, 128, 0, stream>>>(trainOT, W2, b2, Wv, bv, small, out + out_n);
    k_tail<<<((out_n + 255) / 256) * 4, 256, 0, stream>>>(Ws, small, out, out_n);
}

// Round 7
// 112.975 us; speedup vs baseline: 1.9248x; 1.0230x over previous
//
#include <hip/hip_runtime.h>
#include <math.h>

// ---------------- workspace layout (bytes) ----------------
#define O_RPD    (0)                  // row_ptr dst-CSR (~200KB)
#define O_RPS    (256*1024)           // row_ptr src-CSR
#define O_DINV   (512*1024)           // N floats
#define O_SMALL  (768*1024)           // few KB
#define O_Y      (1024*1024)          // N floats: y[u] = h1s_u . w2qk
#define O_RELW   (1280*1024)          // N floats: rel*di
#define O_REL    (1536*1024)          // N floats: rel
#define O_GHD    (1792*1024)          // NB*256 ints [bucket][chunk]
#define O_GHS    (2048*1024)
#define O_GOD    (2304*1024)
#define O_GOS    (2560*1024)
#define O_BSD    (2816*1024)          // NB+1 ints
#define O_BSS    (2944*1024)
#define O_PART   (3072*1024)          // 1024*132*4 = 541KB
#define O_XS     (3712*1024)          // N float4 = 800KB
#define O_SRTD   (4608*1024)          // E uints = 3.2MB
#define O_SRTS   (11776*1024 - 3584*1024)  // = 8192K
#define O_COLD   (11776*1024)
#define O_COLS   (15360*1024)
#define O_H1     (18688*1024)         // N*64 uints = 12.8MB
// small[] float indices:
//   [0..127] w2qk  [128] bias  [132..259] S  [260] R  [264..391] new_trainOT

#define NCHUNK 256
#define ZBLOCKS 1024

static __device__ __forceinline__ unsigned int f2bf(float f) {
    unsigned int u = __float_as_uint(f);
    return (u + 0x7fffu + ((u >> 16) & 1u)) >> 16;            // RNE
}
static __device__ __forceinline__ float bf_lo(unsigned int w) { return __uint_as_float(w << 16); }
static __device__ __forceinline__ float bf_hi(unsigned int w) { return __uint_as_float(w & 0xffff0000u); }

// 256-thread exclusive block scan (4 waves). lds must hold >=4 ints.
static __device__ __forceinline__ int blockExclScan256(int v, volatile int* lds, int t) {
    int lane = t & 63, wid = t >> 6;
    int incl = v;
#pragma unroll
    for (int off = 1; off < 64; off <<= 1) {
        int n = __shfl_up(incl, off);
        if (lane >= off) incl += n;
    }
    if (lane == 63) lds[wid] = incl;
    __syncthreads();
    if (t == 0) {
        int s = 0;
#pragma unroll
        for (int i = 0; i < 4; ++i) { int x = lds[i]; lds[i] = s; s += x; }
    }
    __syncthreads();
    return lds[wid] + incl - v;
}

// ---------------- A1: per-chunk bucket histograms for BOTH orientations ----------------
__global__ void k_hist(const int* __restrict__ eidx, int* __restrict__ ghD,
                       int* __restrict__ ghS, int E, int CS, int NB) {
    __shared__ int lh[256];
    int b = blockIdx.x, t = threadIdx.x;
    const int* arr = blockIdx.y ? eidx : (eidx + E);      // y=0: dst, y=1: src
    int* gh = blockIdx.y ? ghS : ghD;
    lh[t] = 0; __syncthreads();
    int s = b * CS, e = min(E, s + CS);
    for (int i = s + t; i < e; i += 256) atomicAdd(&lh[arr[i] >> 8], 1);
    __syncthreads();
    if (t < NB) gh[t * NCHUNK + b] = lh[t];               // transposed: [bucket][chunk]
}

// ---------------- A2: bucket totals + scans (both orientations, one block) ----------------
__global__ void k_bstart(const int* __restrict__ ghD, const int* __restrict__ ghS,
                         int* __restrict__ bsD, int* __restrict__ bsS, int NB) {
    __shared__ int lds1[4];
    __shared__ int lds2[4];
    int t = threadIdx.x;   // 256
    int vD = 0, vS = 0;
    if (t < NB) {
        const int* rD = ghD + t * NCHUNK;
        const int* rS = ghS + t * NCHUNK;
        for (int b = 0; b < NCHUNK; ++b) { vD += rD[b]; vS += rS[b]; }
    }
    int exD = blockExclScan256(vD, lds1, t);
    if (t <= NB) bsD[t] = exD;
    __syncthreads();
    int exS = blockExclScan256(vS, lds2, t);
    if (t <= NB) bsS[t] = exS;
}

// ---------------- A3: per-bucket chunk offsets (grid NB x 2) ----------------
__global__ void k_goff(const int* __restrict__ ghD, const int* __restrict__ ghS,
                       const int* __restrict__ bsD, const int* __restrict__ bsS,
                       int* __restrict__ goD, int* __restrict__ goS, int NB) {
    __shared__ int lds1[4];
    int nb = blockIdx.x, t = threadIdx.x;
    const int* gh = blockIdx.y ? ghS : ghD;
    const int* bs = blockIdx.y ? bsS : bsD;
    int* go = blockIdx.y ? goS : goD;
    int base = bs[nb];
    int g = gh[nb * NCHUNK + t];
    int gx = blockExclScan256(g, lds1, t);
    go[nb * NCHUNK + t] = base + gx;
}

// ---------------- A4: scatter edges into bucket-sorted runs (grid NCHUNK x 2) ----------------
__global__ void k_scatter(const int* __restrict__ eidx, const int* __restrict__ goD,
                          const int* __restrict__ goS, unsigned int* __restrict__ srtD,
                          unsigned int* __restrict__ srtS, int E, int CS, int NB) {
    __shared__ int lcur[256];
    int b = blockIdx.x, t = threadIdx.x;
    const int* key = blockIdx.y ? eidx : (eidx + E);      // y=0: key=dst, y=1: key=src
    const int* val = blockIdx.y ? (eidx + E) : eidx;
    const int* go  = blockIdx.y ? goS : goD;
    unsigned int* srt = blockIdx.y ? srtS : srtD;
    if (t < NB) lcur[t] = go[t * NCHUNK + b];
    __syncthreads();
    int s = b * CS, e = min(E, s + CS);
    for (int i = s + t; i < e; i += 256) {
        int k = key[i];
        int pos = atomicAdd(&lcur[k >> 8], 1);
        srt[pos] = ((unsigned int)(k & 255) << 16) | (unsigned int)val[i];   // N <= 65536
    }
}

// ---------------- B: per-bucket degree + row_ptr + CSR fill; fwd also dinv/xs4/out-init ----
__global__ void k_build(const unsigned int* __restrict__ srtD, const unsigned int* __restrict__ srtS,
                        const int* __restrict__ bsD, const int* __restrict__ bsS,
                        int* __restrict__ rpD, int* __restrict__ rpS,
                        int* __restrict__ colD, int* __restrict__ colS,
                        float* __restrict__ dinv, const float* __restrict__ x,
                        float4* __restrict__ xs4, const float* __restrict__ bs,
                        float* __restrict__ out, int N, int NB) {
    __shared__ int lcnt[256];
    __shared__ int lpos[256];
    __shared__ int lds1[4];
    int nb = blockIdx.x, t = threadIdx.x;
    bool rev = blockIdx.y != 0;
    const unsigned int* srt = rev ? srtS : srtD;
    const int* bst = rev ? bsS : bsD;
    int* rp  = rev ? rpS : rpD;
    int* col = rev ? colS : colD;
    lcnt[t] = 0; __syncthreads();
    int s = bst[nb], e = bst[nb + 1];
    for (int i = s + t; i < e; i += 256) atomicAdd(&lcnt[srt[i] >> 16], 1);
    __syncthreads();
    int c = lcnt[t];
    int cx = blockExclScan256(c, lds1, t);
    int rpv = s + cx;
    int node = (nb << 8) + t;
    rp[node] = rpv;
    lpos[t] = rpv;
    if (!rev && node < N) {
        float d = rsqrtf((float)(c + 1));   // +1 self-loop
        dinv[node] = d;
        float4 v;
        v.x = x[node * 3] * d; v.y = x[node * 3 + 1] * d; v.z = x[node * 3 + 2] * d; v.w = 0.f;
        xs4[node] = v;
        reinterpret_cast<float2*>(out)[node] = reinterpret_cast<const float2*>(bs)[node];
    }
    __syncthreads();
    for (int i = s + t; i < e; i += 256) {
        unsigned int v = srt[i];
        int p = atomicAdd(&lpos[v >> 16], 1);
        col[p] = (int)(v & 0xffffu);
    }
}

// ---------------- tiny precompute: w2qk / bias ----------------
__global__ void k_tiny1(const float* __restrict__ trainOT, const float* __restrict__ Wq,
                        const float* __restrict__ bq, const float* __restrict__ Wk,
                        const float* __restrict__ bk, const float* __restrict__ W2,
                        const float* __restrict__ b2, float* __restrict__ small) {
    __shared__ float kv[64];
    __shared__ float wqk[128];
    __shared__ float red[128];
    int t = threadIdx.x;   // 128 threads
    if (t < 64) {
        float acc = bk[t];
        for (int j = 0; j < 128; ++j) acc += trainOT[j] * Wk[j * 64 + t];
        kv[t] = acc;
    }
    __syncthreads();
    float accq = 0.f;
    for (int c = 0; c < 64; ++c) accq += Wq[t * 64 + c] * kv[c];
    wqk[t] = accq;
    red[t] = (t < 64) ? bq[t] * kv[t] : 0.f;
    __syncthreads();
    for (int off = 64; off >= 1; off >>= 1) { if (t < off) red[t] += red[t + off]; __syncthreads(); }
    float bqs = red[0];
    __syncthreads();
    float acc2 = 0.f;
    for (int j = 0; j < 128; ++j) acc2 += W2[t * 128 + j] * wqk[j];
    small[t] = acc2;                       // w2qk
    red[t] = b2[t] * wqk[t];
    __syncthreads();
    for (int off = 64; off >= 1; off >>= 1) { if (t < off) red[t] += red[t + off]; __syncthreads(); }
    if (t == 0) small[128] = bqs + red[0]; // bias
}

// ---------------- layer 1: 16 lanes/node; also y[node] = h1s_node . w2qk ----------------
__global__ void k_layer1(const float4* __restrict__ xs4, const int* __restrict__ rpD,
                         const int* __restrict__ colD, const float* __restrict__ dinv,
                         const float* __restrict__ W1, const float* __restrict__ b1,
                         const float* __restrict__ small, unsigned int* __restrict__ h1s,
                         float* __restrict__ y, int N) {
    int t = threadIdx.x;
    int sub = t & 15;
    int node = blockIdx.x * 16 + (t >> 4);
    if (node >= N) return;
    float di = dinv[node];
    int s = rpD[node], e = rpD[node + 1];
    float a0 = 0.f, a1 = 0.f, a2 = 0.f;
    for (int j = s + sub; j < e; j += 16) {
        float4 xv = xs4[colD[j]];
        a0 += xv.x; a1 += xv.y; a2 += xv.z;
    }
    if (sub == 0) { float4 xv = xs4[node]; a0 += xv.x; a1 += xv.y; a2 += xv.z; }
#pragma unroll
    for (int off = 1; off < 16; off <<= 1) {
        a0 += __shfl_xor(a0, off);
        a1 += __shfl_xor(a1, off);
        a2 += __shfl_xor(a2, off);
    }
    a0 *= di; a1 *= di; a2 *= di;
    unsigned int p[4];
    float yl = 0.f;
#pragma unroll
    for (int m = 0; m < 4; ++m) {
        int c = 8 * sub + 2 * m;
        float vlo = fmaxf(a0 * W1[c]     + a1 * W1[128 + c]     + a2 * W1[256 + c]     + b1[c],     0.f) * di;
        float vhi = fmaxf(a0 * W1[c + 1] + a1 * W1[128 + c + 1] + a2 * W1[256 + c + 1] + b1[c + 1], 0.f) * di;
        p[m] = f2bf(vlo) | (f2bf(vhi) << 16);
        // y uses the bf16-rounded values (matches what k_z will read back)
        yl += bf_lo(p[m]) * small[c] + bf_hi(p[m]) * small[c + 1];
    }
    uint4 st; st.x = p[0]; st.y = p[1]; st.z = p[2]; st.w = p[3];
    reinterpret_cast<uint4*>(h1s + (size_t)node * 64)[sub] = st;
#pragma unroll
    for (int off = 1; off < 16; off <<= 1) yl += __shfl_xor(yl, off);
    if (sub == 0) y[node] = yl;
}

// ---------------- dv/rel: scalar aggregation of y over dst-CSR ----------------
__global__ void k_dv(const float* __restrict__ y, const int* __restrict__ rpD,
                     const int* __restrict__ colD, const float* __restrict__ dinv,
                     const float* __restrict__ small, float* __restrict__ relw,
                     float* __restrict__ rel, int N) {
    int t = threadIdx.x;
    int sub = t & 15;
    int node = blockIdx.x * 16 + (t >> 4);
    if (node >= N) return;
    float di = dinv[node];
    int s = rpD[node], e = rpD[node + 1];
    float acc = (sub == 0) ? y[node] : 0.f;
    for (int j = s + sub; j < e; j += 16) acc += y[colD[j]];
#pragma unroll
    for (int off = 1; off < 16; off <<= 1) acc += __shfl_xor(acc, off);
    float z = (acc * di + small[128]) * 0.125f;     // / sqrt(64)
    float r = 1.f / (1.f + __expf(-z));
    if (sub == 0) { rel[node] = r; relw[node] = r * di; }
}

// ---------------- z + S: z[u] = relw[u] + sum_{u->n} relw[n]; S += z[u]*h1s_u; R += rel[u] ----
__global__ void k_z(const unsigned int* __restrict__ h1s, const int* __restrict__ rpS,
                    const int* __restrict__ colS, const float* __restrict__ relw,
                    const float* __restrict__ rel, float* __restrict__ part, int N) {
    int t = threadIdx.x, lane = t & 63, wid = t >> 6;
    int sub = lane & 15;
    float acc[8];
#pragma unroll
    for (int j = 0; j < 8; ++j) acc[j] = 0.f;
    float Racc = 0.f;
    for (int node = blockIdx.x * 16 + (t >> 4); node < N; node += ZBLOCKS * 16) {
        int s = rpS[node], e = rpS[node + 1];
        float w = (sub == 0) ? relw[node] : 0.f;
        for (int j = s + sub; j < e; j += 16) w += relw[colS[j]];
#pragma unroll
        for (int off = 1; off < 16; off <<= 1) w += __shfl_xor(w, off);
        uint4 v = reinterpret_cast<const uint4*>(h1s + (size_t)node * 64)[sub];
        acc[0] += w * bf_lo(v.x); acc[1] += w * bf_hi(v.x);
        acc[2] += w * bf_lo(v.y); acc[3] += w * bf_hi(v.y);
        acc[4] += w * bf_lo(v.z); acc[5] += w * bf_hi(v.z);
        acc[6] += w * bf_lo(v.w); acc[7] += w * bf_hi(v.w);
        if (sub == 0) Racc += rel[node];
    }
#pragma unroll
    for (int j = 0; j < 8; ++j) {
        acc[j] += __shfl_xor(acc[j], 16);
        acc[j] += __shfl_xor(acc[j], 32);
    }
    Racc += __shfl_xor(Racc, 16);
    Racc += __shfl_xor(Racc, 32);
    __shared__ float sS[4][132];
    if (lane < 16) {
#pragma unroll
        for (int j = 0; j < 8; ++j) sS[wid][8 * sub + j] = acc[j];
    }
    if (lane == 0) sS[wid][128] = Racc;
    __syncthreads();
    if (t < 129) part[blockIdx.x * 132 + t] = sS[0][t] + sS[1][t] + sS[2][t] + sS[3][t];
}

__global__ void k_reduce_part(const float* __restrict__ part, int nblocks, float* __restrict__ small) {
    int c = blockIdx.x;   // 0..128
    float acc = 0.f;
    for (int b = threadIdx.x; b < nblocks; b += blockDim.x) acc += part[b * 132 + c];
    __shared__ float sd[256];
    sd[threadIdx.x] = acc; __syncthreads();
    for (int off = 128; off; off >>= 1) { if (threadIdx.x < off) sd[threadIdx.x] += sd[threadIdx.x + off]; __syncthreads(); }
    if (threadIdx.x == 0) small[132 + c] = sd[0];
}

// ---------------- newT = trainOT + (S@W2 + R*b2)@Wv + R*bv ----------------
__global__ void k_tiny2(const float* __restrict__ trainOT, const float* __restrict__ W2,
                        const float* __restrict__ b2, const float* __restrict__ Wv,
                        const float* __restrict__ bv, float* __restrict__ small,
                        float* __restrict__ out_tail) {
    __shared__ float t1[128];
    int t = threadIdx.x;   // 128
    float R = small[260];
    float acc = R * b2[t];
    for (int j = 0; j < 128; ++j) acc += small[132 + j] * W2[j * 128 + t];
    t1[t] = acc; __syncthreads();
    float acc2 = R * bv[t];
    for (int j = 0; j < 128; ++j) acc2 += t1[j] * Wv[j * 128 + t];
    float nt = trainOT[t] + acc2;
    small[264 + t] = nt;
    out_tail[t] = nt;
}

// ---------------- speak: out += nt @ Ws, K split 4-way, out pre-inited to bs ----------------
__global__ void k_tail(const float* __restrict__ Ws, const float* __restrict__ small,
                       float* __restrict__ out, int out_n) {
    int ks = blockIdx.x & 3;
    int j = ((blockIdx.x >> 2) << 8) + threadIdx.x;
    if (j >= out_n) return;
    const float* w = Ws + (size_t)(ks * 32) * out_n + j;
    const float* nt = small + 264 + ks * 32;
    float acc = 0.f;
#pragma unroll 8
    for (int k = 0; k < 32; ++k) acc += nt[k] * w[(size_t)k * out_n];
    atomicAdd(&out[j], acc);
}

extern "C" void kernel_launch(void* const* d_in, const int* in_sizes, int n_in,
                              void* d_out, int out_size, void* d_ws, size_t ws_size,
                              hipStream_t stream) {
    const float* features = (const float*)d_in[0];
    const int*   eidx     = (const int*)d_in[1];
    const float* trainOT  = (const float*)d_in[2];
    const float* W1 = (const float*)d_in[3];
    const float* b1 = (const float*)d_in[4];
    const float* W2 = (const float*)d_in[5];
    const float* b2 = (const float*)d_in[6];
    const float* Wq = (const float*)d_in[7];
    const float* bq = (const float*)d_in[8];
    const float* Wk = (const float*)d_in[9];
    const float* bk = (const float*)d_in[10];
    const float* Wv = (const float*)d_in[11];
    const float* bv = (const float*)d_in[12];
    const float* Ws = (const float*)d_in[13];
    const float* bs = (const float*)d_in[14];

    int N = in_sizes[0] / 3;
    int E = in_sizes[1] / 2;
    int NB = (N + 255) >> 8;
    int CS = (E + NCHUNK - 1) / NCHUNK;

    char* ws = (char*)d_ws;
    int*   rpD   = (int*)(ws + O_RPD);
    int*   rpS   = (int*)(ws + O_RPS);
    float* dinv  = (float*)(ws + O_DINV);
    float* small = (float*)(ws + O_SMALL);
    float* y     = (float*)(ws + O_Y);
    float* relw  = (float*)(ws + O_RELW);
    float* rel   = (float*)(ws + O_REL);
    int*   ghD   = (int*)(ws + O_GHD);
    int*   ghS   = (int*)(ws + O_GHS);
    int*   goD   = (int*)(ws + O_GOD);
    int*   goS   = (int*)(ws + O_GOS);
    int*   bsD   = (int*)(ws + O_BSD);
    int*   bsS   = (int*)(ws + O_BSS);
    float* part  = (float*)(ws + O_PART);
    float4* xs4  = (float4*)(ws + O_XS);
    unsigned int* srtD = (unsigned int*)(ws + O_SRTD);
    unsigned int* srtS = (unsigned int*)(ws + O_SRTS);
    int*   colD  = (int*)(ws + O_COLD);
    int*   colS  = (int*)(ws + O_COLS);
    unsigned int* h1s = (unsigned int*)(ws + O_H1);
    float* out   = (float*)d_out;
    int out_n = out_size - 128;

    k_tiny1<<<1, 128, 0, stream>>>(trainOT, Wq, bq, Wk, bk, W2, b2, small);
    k_hist<<<dim3(NCHUNK, 2), 256, 0, stream>>>(eidx, ghD, ghS, E, CS, NB);
    k_bstart<<<1, 256, 0, stream>>>(ghD, ghS, bsD, bsS, NB);
    k_goff<<<dim3(NB, 2), 256, 0, stream>>>(ghD, ghS, bsD, bsS, goD, goS, NB);
    k_scatter<<<dim3(NCHUNK, 2), 256, 0, stream>>>(eidx, goD, goS, srtD, srtS, E, CS, NB);
    k_build<<<dim3(NB, 2), 256, 0, stream>>>(srtD, srtS, bsD, bsS, rpD, rpS, colD, colS,
                                             dinv, features, xs4, bs, out, N, NB);
    k_layer1<<<(N + 15) / 16, 256, 0, stream>>>(xs4, rpD, colD, dinv, W1, b1, small, h1s, y, N);
    k_dv<<<(N + 15) / 16, 256, 0, stream>>>(y, rpD, colD, dinv, small, relw, rel, N);
    k_z<<<ZBLOCKS, 256, 0, stream>>>(h1s, rpS, colS, relw, rel, part, N);
    k_reduce_part<<<129, 256, 0, stream>>>(part, ZBLOCKS, small);
    k_tiny2<<<1, 128, 0, stream>>>(trainOT, W2, b2, Wv, bv, small, out + out_n);
    k_tail<<<((out_n + 255) / 256) * 4, 256, 0, stream>>>(Ws, small, out, out_n);
}